// Round 4
// baseline (864.590 us; speedup 1.0000x reference)
//
#include <hip/hip_runtime.h>
#include <hip/hip_bf16.h>

// Problem constants (N=64, D=64, H=64, W=64, K=512)
#define VQ_D   64
#define VQ_K   512
#define VQ_HW  4096
#define VQ_M   262144
#define VQ_LOSS_OFF 16777216
#define VQ_IDX_OFF  16777217
#define VQ_MARGIN   4e-4f

typedef __bf16 bf16x8v __attribute__((ext_vector_type(8)));
typedef float  f32x16  __attribute__((ext_vector_type(16)));

union BF8 { unsigned short u[8]; uint4 q4; bf16x8v v; };

// fp32 -> bf16 round-to-nearest-even
__device__ __forceinline__ unsigned short f2bf(float f) {
    unsigned u = __builtin_bit_cast(unsigned, f);
    u += 0x7FFFu + ((u >> 16) & 1u);
    return (unsigned short)(u >> 16);
}

// ---------------------------------------------------------------------------
// Prep: esq[k] (numpy pairwise, bitwise), bf16 B-fragments in MFMA layout,
// zero loss/cnt. B-frag layout for v_mfma_f32_32x32x16_bf16:
//   lane l holds B[k=(l>>5)*8+j][col=l&31]; frag (tile t, quarter q):
//   code = t*32 + col, d = q*16 + (l>>5)*8 + j.
// ---------------------------------------------------------------------------
__global__ void vq_prep(const float* __restrict__ emb, float* __restrict__ esq,
                        unsigned short* __restrict__ bfrag,
                        double* __restrict__ loss_acc, int* __restrict__ cnt) {
#pragma clang fp contract(off)
    int k = blockIdx.x * 256 + threadIdx.x;
    if (blockIdx.x == 0 && threadIdx.x == 0) { *loss_acc = 0.0; *cnt = 0; }
    if (k < VQ_K) {
        const float* e = emb + k * VQ_D;
        // esq: numpy pairwise (8 accs stride-8, tree combine), rounded products
        float p[VQ_D];
#pragma unroll
        for (int d = 0; d < VQ_D; ++d) p[d] = e[d] * e[d];
        float r[8];
#pragma unroll
        for (int j = 0; j < 8; ++j) r[j] = p[j];
#pragma unroll
        for (int i = 8; i < VQ_D; i += 8)
#pragma unroll
            for (int j = 0; j < 8; ++j) r[j] += p[i + j];
        esq[k] = ((r[0] + r[1]) + (r[2] + r[3])) + ((r[4] + r[5]) + (r[6] + r[7]));

        // B-fragments
        uint4* bg = (uint4*)bfrag;
        int t = k >> 5, c = k & 31;
#pragma unroll
        for (int q = 0; q < 4; ++q)
#pragma unroll
            for (int hi = 0; hi < 2; ++hi) {
                BF8 tmp;
#pragma unroll
                for (int j = 0; j < 8; ++j)
                    tmp.u[j] = f2bf(e[q * 16 + hi * 8 + j]);
                bg[(t * 4 + q) * 64 + hi * 32 + c] = tmp.q4;
            }
    }
}

// ---------------------------------------------------------------------------
// Screen: bf16 MFMA approximate scores s = esq - 2*dot, online top-2 per row,
// flag rows with gap <= margin for exact rescore.
// Block = 256 thr (4 waves), handles 512 points; 64 KB dynamic LDS of B-frags.
// ---------------------------------------------------------------------------
__global__ __launch_bounds__(256) void vq_screen(
        const float* __restrict__ z_e,
        const unsigned short* __restrict__ bfrag,
        const float* __restrict__ esq,
        float* __restrict__ out_idx,
        int* __restrict__ cnt,
        int* __restrict__ flag_list)
{
    extern __shared__ uint4 smem[];
    const int tid  = threadIdx.x;
    const int l    = tid & 63;
    const int w    = tid >> 6;
    const int c31  = l & 31;
    const int half = l >> 5;

    // stage all B-frags (64 KB) to LDS
    const uint4* bg = (const uint4*)bfrag;
#pragma unroll
    for (int i = 0; i < 16; ++i) smem[i * 256 + tid] = bg[i * 256 + tid];
    __syncthreads();

    const int m_blk = blockIdx.x * 512;          // 512 points per block, same n
    const int n     = m_blk >> 12;
    const float* zbase = z_e + (size_t)n * (VQ_D * VQ_HW);

    for (int mt = 0; mt < 4; ++mt) {
        const int chunk = mt * 4 + w;            // 0..15
        const int m_row = m_blk + chunk * 32 + c31;  // this lane's A row
        const int hw    = m_row & 4095;

        // A-frags: lane holds A[m=l&31][k=(l>>5)*8+j], d = q*16 + k
        bf16x8v a[4];
#pragma unroll
        for (int q = 0; q < 4; ++q) {
            BF8 t;
#pragma unroll
            for (int j = 0; j < 8; ++j) {
                int d = q * 16 + half * 8 + j;
                t.u[j] = f2bf(zbase[d * VQ_HW + hw]);
            }
            a[q] = t.v;
        }

        float m1[16], m2[16]; int i1[16];
#pragma unroll
        for (int r = 0; r < 16; ++r) { m1[r] = 3.4e38f; m2[r] = 3.4e38f; i1[r] = 0; }

        for (int t = 0; t < 16; ++t) {           // 16 code-tiles of 32
            float esq_c = esq[t * 32 + c31];
            f32x16 acc;
#pragma unroll
            for (int r = 0; r < 16; ++r) acc[r] = 0.f;
#pragma unroll
            for (int q = 0; q < 4; ++q) {
                bf16x8v b = __builtin_bit_cast(bf16x8v, smem[(t * 4 + q) * 64 + l]);
                acc = __builtin_amdgcn_mfma_f32_32x32x16_bf16(a[q], b, acc, 0, 0, 0);
            }
            const int code = t * 32 + c31;
#pragma unroll
            for (int r = 0; r < 16; ++r) {
                float s   = fmaf(-2.f, acc[r], esq_c);
                bool  lt  = s < m1[r];
                float nm2 = fminf(m2[r], fmaxf(m1[r], s));
                m1[r] = fminf(m1[r], s);
                m2[r] = nm2;
                i1[r] = lt ? code : i1[r];
            }
        }

        // cross-lane top-2 merge across the 32 lanes sharing each row
#pragma unroll
        for (int off = 1; off <= 16; off <<= 1) {
#pragma unroll
            for (int r = 0; r < 16; ++r) {
                float om1 = __shfl_xor(m1[r], off, 64);
                float om2 = __shfl_xor(m2[r], off, 64);
                int   oi  = __shfl_xor(i1[r], off, 64);
                bool  olt = om1 < m1[r];
                float nm2 = fminf(fminf(m2[r], om2), fmaxf(m1[r], om1));
                m1[r] = olt ? om1 : m1[r];
                i1[r] = olt ? oi  : i1[r];
                m2[r] = nm2;
            }
        }

        if (c31 == 0) {                          // lanes 0 and 32 write
#pragma unroll
            for (int r = 0; r < 16; ++r) {
                int row   = (r & 3) + 8 * (r >> 2) + 4 * half;  // C/D layout
                int m_out = m_blk + chunk * 32 + row;
                out_idx[m_out] = (float)i1[r];
                if (m2[r] - m1[r] <= VQ_MARGIN) {
                    int pos = atomicAdd(cnt, 1);
                    flag_list[pos] = m_out;
                }
            }
        }
    }
}

// ---------------------------------------------------------------------------
// Rescore flagged points with the bitwise-numpy fp32 formula (round-3 logic).
// ---------------------------------------------------------------------------
__global__ __launch_bounds__(256) void vq_rescore(
        const float* __restrict__ z_e,
        const float* __restrict__ emb,
        const float* __restrict__ esq,
        float* __restrict__ out_idx,
        const int* __restrict__ cnt,
        const int* __restrict__ flag_list)
{
#pragma clang fp contract(off)
    const int total = *cnt;
    for (int i = blockIdx.x * 256 + threadIdx.x; i < total; i += 256 * 256) {
        const int m  = flag_list[i];
        const int n  = m >> 12;
        const int hw = m & 4095;
        const float* zp = z_e + (size_t)n * (VQ_D * VQ_HW) + hw;
        float z[VQ_D];
#pragma unroll
        for (int d = 0; d < VQ_D; ++d) z[d] = zp[d * VQ_HW];

        float p[VQ_D];
#pragma unroll
        for (int d = 0; d < VQ_D; ++d) p[d] = z[d] * z[d];
        float r[8];
#pragma unroll
        for (int j = 0; j < 8; ++j) r[j] = p[j];
#pragma unroll
        for (int ii = 8; ii < VQ_D; ii += 8)
#pragma unroll
            for (int j = 0; j < 8; ++j) r[j] += p[ii + j];
        const float zsq = ((r[0] + r[1]) + (r[2] + r[3])) + ((r[4] + r[5]) + (r[6] + r[7]));

        float best = 3.4e38f;
        int   bi   = 0;
        for (int k = 0; k < VQ_K; k += 2) {
            const float* e0 = emb + k * VQ_D;
            const float* e1 = e0 + VQ_D;
            float a0 = 0.f, a1 = 0.f;
#pragma unroll
            for (int d = 0; d < VQ_D; ++d) {
                a0 = __builtin_fmaf(z[d], e0[d], a0);
                a1 = __builtin_fmaf(z[d], e1[d], a1);
            }
            float d0 = (zsq + esq[k])     - 2.0f * a0;
            float d1 = (zsq + esq[k + 1]) - 2.0f * a1;
            if (d0 < best) { best = d0; bi = k; }
            if (d1 < best) { best = d1; bi = k + 1; }
        }
        out_idx[m] = (float)bi;
    }
}

// ---------------------------------------------------------------------------
// Output: gather winning row, write z_q (straight-through value), loss.
// ---------------------------------------------------------------------------
__global__ __launch_bounds__(256) void vq_out(
        const float* __restrict__ z_e,
        const float* __restrict__ emb,
        const float* __restrict__ out_idx,
        float* __restrict__ out,
        double* __restrict__ loss_acc)
{
    const int m  = blockIdx.x * 256 + threadIdx.x;
    const int n  = m >> 12;
    const int hw = m & 4095;
    const int bi = (int)out_idx[m];

    const float* eb = emb + bi * VQ_D;
    const float* zp = z_e + (size_t)n * (VQ_D * VQ_HW) + hw;
    float* op = out + (size_t)n * (VQ_D * VQ_HW) + hw;
    float lsum = 0.f;
#pragma unroll
    for (int d = 0; d < VQ_D; ++d) {
        float q = eb[d];
        op[d * VQ_HW] = q;
        float diff = zp[d * VQ_HW] - q;
        lsum = __builtin_fmaf(diff, diff, lsum);
    }

    for (int off = 32; off > 0; off >>= 1)
        lsum += __shfl_down(lsum, off, 64);

    __shared__ float wsum[4];
    const int lane = threadIdx.x & 63;
    const int wid  = threadIdx.x >> 6;
    if (lane == 0) wsum[wid] = lsum;
    __syncthreads();
    if (threadIdx.x == 0) {
        float b = wsum[0] + wsum[1] + wsum[2] + wsum[3];
        atomicAdd(loss_acc, (double)b);
    }
}

__global__ void vq_fin(const double* __restrict__ loss_acc, float* __restrict__ out) {
    if (threadIdx.x == 0)
        out[VQ_LOSS_OFF] = (float)(*loss_acc / 16777216.0);
}

extern "C" void kernel_launch(void* const* d_in, const int* in_sizes, int n_in,
                              void* d_out, int out_size, void* d_ws, size_t ws_size,
                              hipStream_t stream) {
    const float* z_e = (const float*)d_in[0];
    const float* emb = (const float*)d_in[1];
    float* out = (float*)d_out;
    float* out_idx = out + VQ_IDX_OFF;

    // ws layout:
    //   0      : double loss_acc            (8 B)
    //   8      : int cnt                    (4 B + 4 pad)
    //   16     : float esq[512]             (2048 B)   -> ends 2064
    //   2064   : ushort bfrag[32768]        (65536 B)  -> ends 67600 (16-aligned)
    //   67600  : int flag_list[262144]      (1 MB)
    char* ws = (char*)d_ws;
    double* loss_acc       = (double*)ws;
    int*    cnt            = (int*)(ws + 8);
    float*  esq            = (float*)(ws + 16);
    unsigned short* bfrag  = (unsigned short*)(ws + 2064);
    int*    flag_list      = (int*)(ws + 67600);

    vq_prep<<<2, 256, 0, stream>>>(emb, esq, bfrag, loss_acc, cnt);
    vq_screen<<<512, 256, 65536, stream>>>(z_e, bfrag, esq, out_idx, cnt, flag_list);
    vq_rescore<<<256, 256, 0, stream>>>(z_e, emb, esq, out_idx, cnt, flag_list);
    vq_out<<<VQ_M / 256, 256, 0, stream>>>(z_e, emb, out_idx, out, loss_acc);
    vq_fin<<<1, 64, 0, stream>>>(loss_acc, out);
}